// Round 1
// baseline (6532.830 us; speedup 1.0000x reference)
//
#include <hip/hip_runtime.h>
#include <stdint.h>
#include <stddef.h>

// Variational-dropout LSTM, SEQ=256, B=64, IN=H=1024, fp32 I/O.
//
// Structure:
//  - prep_kernel: converts inputs to bf16 and PRE-SWIZZLES them into MFMA
//    fragment order (lane-contiguous 16B chunks) so the step kernel's global
//    loads are perfectly coalesced. Also computes bias = b_ih + b_hh (fp32),
//    copies c0, builds mh0 = h0*mask_h (swizzled bf16).
//  - lstm_step (x256, stream-ordered): 64 blocks x 256 threads. Block bk owns
//    h-columns [bk*16, bk*16+16). Wave w owns batch rows [w*16, w*16+16).
//    Each wave accumulates 4 gate tiles (i,f,g,o) of 16x16 via
//    mfma_f32_16x16x32_bf16 over K=1024 (x-projection, folded in) +
//    K=1024 (recurrent), then applies the LSTM cell in fp32 and writes
//    h (fp32 out), c (fp32 ws), and mh = h*mask_h (bf16, swizzled, ping-pong).

#define SEQ  256
#define BB   64
#define HHID 1024

typedef __attribute__((ext_vector_type(8))) __bf16 bf16x8;
typedef __attribute__((ext_vector_type(4))) float  f32x4;

__device__ __forceinline__ unsigned short f2bf(float f) {
  union { float f; unsigned u; } v; v.f = f;
  unsigned r = v.u + 0x7FFFu + ((v.u >> 16) & 1u);   // round-to-nearest-even
  return (unsigned short)(r >> 16);
}

// ws layout (bytes):
//  Wihp  @ 0          : 4096*1024 bf16 = 8388608   swizzled [t=q*64+bk][kw][l][e]
//  Whhp  @ 8388608    : 8388608
//  Ap    @ 16777216   : 256*64*1024 bf16 = 33554432 swizzled [s][w][kw][l][e]
//  mhp0  @ 50331648   : 64*1024 bf16 = 131072       swizzled [w][kw][l][e]
//  mhp1  @ 50462720   : 131072
//  c     @ 50593792   : 64*1024 f32 = 262144
//  bias  @ 50855936   : 4096 f32 = 16384
// total 50872320 bytes

__global__ __launch_bounds__(256) void prep_kernel(
    const float* __restrict__ x, const float* __restrict__ h0,
    const float* __restrict__ c0, const float* __restrict__ mask_x,
    const float* __restrict__ mask_h, const float* __restrict__ Wih,
    const float* __restrict__ Whh, const float* __restrict__ bih,
    const float* __restrict__ bhh,
    unsigned short* __restrict__ Wihp, unsigned short* __restrict__ Whhp,
    unsigned short* __restrict__ Ap, unsigned short* __restrict__ mhp0,
    float* __restrict__ c, float* __restrict__ bias)
{
  const unsigned idx = blockIdx.x * 256u + threadIdx.x;  // grid covers 16777216

  // Ap[s][w][kw][l][e] = bf16( x[s][m][k] * mask_x[m][k] ),
  //   m = w*16 + (l&15), k = kw*32 + (l>>4)*8 + e
  {
    const unsigned e  = idx & 7u;
    const unsigned l  = (idx >> 3) & 63u;
    const unsigned kw = (idx >> 9) & 31u;
    const unsigned w  = (idx >> 14) & 3u;
    const unsigned s  = idx >> 16;
    const unsigned m  = w * 16u + (l & 15u);
    const unsigned k  = kw * 32u + (l >> 4) * 8u + e;
    const float v = x[((size_t)s * 64u + m) * 1024u + k] * mask_x[m * 1024u + k];
    Ap[idx] = f2bf(v);
  }
  // W swizzle: Wp[t][kw][l][e] = W[n][k], n = (t>>6)*1024 + (t&63)*16 + (l&15)
  if (idx < 4194304u) {
    const unsigned e  = idx & 7u;
    const unsigned l  = (idx >> 3) & 63u;
    const unsigned kw = (idx >> 9) & 31u;
    const unsigned t  = idx >> 14;
    const unsigned n  = (t >> 6) * 1024u + (t & 63u) * 16u + (l & 15u);
    const unsigned k  = kw * 32u + (l >> 4) * 8u + e;
    Wihp[idx] = f2bf(Wih[n * 1024u + k]);
    Whhp[idx] = f2bf(Whh[n * 1024u + k]);
  }
  // mh0 swizzle + c copy
  if (idx < 65536u) {
    const unsigned e  = idx & 7u;
    const unsigned l  = (idx >> 3) & 63u;
    const unsigned kw = (idx >> 9) & 31u;
    const unsigned w  = idx >> 14;
    const unsigned m  = w * 16u + (l & 15u);
    const unsigned k  = kw * 32u + (l >> 4) * 8u + e;
    mhp0[idx] = f2bf(h0[m * 1024u + k] * mask_h[m * 1024u + k]);
    c[idx] = c0[idx];
  }
  if (idx < 4096u) bias[idx] = bih[idx] + bhh[idx];
}

__global__ __launch_bounds__(256) void lstm_step(
    const unsigned short* __restrict__ Ap,    // [256][4][32][64][8] bf16
    const unsigned short* __restrict__ Wihp,  // [256][32][64][8]
    const unsigned short* __restrict__ Whhp,  // [256][32][64][8]
    const float* __restrict__ bias,           // [4096]
    const unsigned short* __restrict__ mhp_in,   // [4][32][64][8]
    unsigned short* __restrict__ mhp_out,
    float* __restrict__ c,                    // [64][1024]
    const float* __restrict__ mask_h,         // [64][1024]
    float* __restrict__ out,                  // [256*64*1024 + 65536 + 65536]
    int s)
{
  const int tid  = threadIdx.x;
  const int w    = tid >> 6;      // wave = M-tile (batches w*16..w*16+15)
  const int l    = tid & 63;
  const int lr   = l & 15;
  const int quad = l >> 4;
  const int bk   = blockIdx.x;    // h-column group (16 cols)

  f32x4 acc[4] = { {0.f,0.f,0.f,0.f}, {0.f,0.f,0.f,0.f},
                   {0.f,0.f,0.f,0.f}, {0.f,0.f,0.f,0.f} };

  const bf16x8* __restrict__ aX = (const bf16x8*)Ap + ((size_t)(s * 4 + w) * 32) * 64 + l;
  const bf16x8* __restrict__ aH = (const bf16x8*)mhp_in + ((size_t)w * 32) * 64 + l;
  const bf16x8* __restrict__ wI = (const bf16x8*)Wihp;
  const bf16x8* __restrict__ wH = (const bf16x8*)Whhp;

  // x-projection: gates += (x*mask_x) @ W_ih^T   (K = 1024)
  #pragma unroll 4
  for (int kw = 0; kw < 32; ++kw) {
    bf16x8 a = aX[kw * 64];
    #pragma unroll
    for (int q = 0; q < 4; ++q) {
      bf16x8 b = wI[(((q * 64 + bk) * 32 + kw) * 64) + l];
      acc[q] = __builtin_amdgcn_mfma_f32_16x16x32_bf16(a, b, acc[q], 0, 0, 0);
    }
  }
  // recurrent: gates += (h*mask_h) @ W_hh^T      (K = 1024)
  #pragma unroll 4
  for (int kw = 0; kw < 32; ++kw) {
    bf16x8 a = aH[kw * 64];
    #pragma unroll
    for (int q = 0; q < 4; ++q) {
      bf16x8 b = wH[(((q * 64 + bk) * 32 + kw) * 64) + l];
      acc[q] = __builtin_amdgcn_mfma_f32_16x16x32_bf16(a, b, acc[q], 0, 0, 0);
    }
  }

  // Epilogue: D layout col = lane&15, row = quad*4 + r (within 16x16 tile).
  const int j = bk * 16 + lr;           // h column
  const float bi = bias[j];
  const float bf_ = bias[1024 + j];
  const float bg = bias[2048 + j];
  const float bo = bias[3072 + j];
  // swizzled mh_out addressing pieces for column j
  const int qp  = ((bk & 1) << 1) | (lr >> 3);  // quad in swizzled layout
  const int e   = lr & 7;
  const int kwj = bk >> 1;

  #pragma unroll
  for (int r = 0; r < 4; ++r) {
    const int m = w * 16 + quad * 4 + r;   // batch row
    const float ip = acc[0][r] + bi;
    const float fp = acc[1][r] + bf_;
    const float gp = acc[2][r] + bg;
    const float op = acc[3][r] + bo;
    const float iv = 1.f / (1.f + __expf(-ip));
    const float fv = 1.f / (1.f + __expf(-fp));
    const float gv = tanhf(gp);
    const float ov = 1.f / (1.f + __expf(-op));
    const float cold = c[m * 1024 + j];
    const float cn = fv * cold + iv * gv;
    const float hn = ov * tanhf(cn);
    c[m * 1024 + j] = cn;
    out[((size_t)s * 64 + m) * 1024 + j] = hn;
    const int lp = (qp << 4) | (m & 15);
    mhp_out[((((m >> 4) * 32 + kwj) * 64) + lp) * 8 + e] =
        f2bf(hn * mask_h[m * 1024 + j]);
    if (s == SEQ - 1) {
      out[(size_t)SEQ * 64 * 1024 + m * 1024 + j] = hn;                 // h_n
      out[(size_t)SEQ * 64 * 1024 + 65536 + m * 1024 + j] = cn;        // c_n
    }
  }
}

extern "C" void kernel_launch(void* const* d_in, const int* in_sizes, int n_in,
                              void* d_out, int out_size, void* d_ws, size_t ws_size,
                              hipStream_t stream)
{
  const float* x      = (const float*)d_in[0];
  const float* h0     = (const float*)d_in[1];
  const float* c0     = (const float*)d_in[2];
  const float* mask_x = (const float*)d_in[3];
  const float* mask_h = (const float*)d_in[4];
  const float* Wih    = (const float*)d_in[5];
  const float* Whh    = (const float*)d_in[6];
  const float* bih    = (const float*)d_in[7];
  const float* bhh    = (const float*)d_in[8];
  float* out = (float*)d_out;

  char* ws = (char*)d_ws;
  unsigned short* Wihp = (unsigned short*)(ws + 0);
  unsigned short* Whhp = (unsigned short*)(ws + 8388608);
  unsigned short* Ap   = (unsigned short*)(ws + 16777216);
  unsigned short* mhp0 = (unsigned short*)(ws + 50331648);
  unsigned short* mhp1 = (unsigned short*)(ws + 50462720);
  float* c    = (float*)(ws + 50593792);
  float* bias = (float*)(ws + 50855936);

  hipLaunchKernelGGL(prep_kernel, dim3(65536), dim3(256), 0, stream,
                     x, h0, c0, mask_x, mask_h, Wih, Whh, bih, bhh,
                     Wihp, Whhp, Ap, mhp0, c, bias);

  for (int s = 0; s < SEQ; ++s) {
    const unsigned short* mi = (s & 1) ? mhp1 : mhp0;
    unsigned short*       mo = (s & 1) ? mhp0 : mhp1;
    hipLaunchKernelGGL(lstm_step, dim3(64), dim3(256), 0, stream,
                       Ap, Wihp, Whhp, bias, mi, mo, c, mask_h, out, s);
  }
}